// Round 1
// baseline (123.072 us; speedup 1.0000x reference)
//
#include <hip/hip_runtime.h>

#define C_DIM 256
#define W_DIM 4096
#define WI 62            // interior columns per chunk
#define NCH 67           // ceil(4096/62)
#define LDS_BYTES 75008

typedef unsigned short u16;
typedef short s16x8 __attribute__((ext_vector_type(8)));
typedef float f32x16 __attribute__((ext_vector_type(16)));

__device__ __forceinline__ u16 f2b(float f) {
  unsigned x = __builtin_bit_cast(unsigned, f);
  x = x + 0x7FFFu + ((x >> 16) & 1u);          // RNE to bf16 (inputs finite)
  return (u16)(x >> 16);
}
__device__ __forceinline__ float b2f(u16 u) {
  return __builtin_bit_cast(float, ((unsigned)u) << 16);
}

// ---------------- prep kernel ----------------
// ws layout: [0,131072) M bf16 [256][256]; [131072,262144) Wv bf16;
//            [262144) u0[256] f32; [263168) u1[256] f32; [264192) c0 f32
// blocks 0..255 : M[i][j] = sum_a Wq[a][i]*Wk[a][j]
// block 256     : u0[j]=sum_a bq[a]*Wk[a][j]; u1[j]=sum_a bk[a]*Wq[a][j]; c0=bq.bk
// blocks 257..320: Wv -> bf16
__global__ __launch_bounds__(256) void prep_kernel(
    const float* __restrict__ Wq, const float* __restrict__ bq,
    const float* __restrict__ Wk, const float* __restrict__ bk,
    const float* __restrict__ Wv, char* __restrict__ ws) {
  u16* Mb   = (u16*)ws;
  u16* Wvb  = (u16*)(ws + 131072);
  float* u0 = (float*)(ws + 262144);
  float* u1 = (float*)(ws + 263168);
  float* c0p = (float*)(ws + 264192);
  int bid = blockIdx.x, t = threadIdx.x;
  if (bid < 256) {
    __shared__ float Wqs[256*17];
    __shared__ float Wks[256*17];
    int i0 = (bid >> 4) << 4, j0 = (bid & 15) << 4;
    for (int it = 0; it < 16; ++it) {
      int e = t + 256*it; int a = e >> 4, ii = e & 15;
      Wqs[a*17+ii] = Wq[a*256 + i0 + ii];
      Wks[a*17+ii] = Wk[a*256 + j0 + ii];
    }
    __syncthreads();
    int ii = t >> 4, jj = t & 15;
    float acc = 0.f;
    #pragma unroll 8
    for (int a = 0; a < 256; ++a) acc += Wqs[a*17+ii] * Wks[a*17+jj];
    Mb[(i0+ii)*256 + j0 + jj] = f2b(acc);
  } else if (bid == 256) {
    int j = t;
    float a0 = 0.f, a1 = 0.f;
    #pragma unroll 4
    for (int a = 0; a < 256; ++a) {
      a0 += bq[a] * Wk[a*256 + j];
      a1 += bk[a] * Wq[a*256 + j];
    }
    u0[j] = a0; u1[j] = a1;
    __shared__ float red[256];
    red[t] = bq[t] * bk[t];
    __syncthreads();
    if (t == 0) { float s = 0.f; for (int a = 0; a < 256; ++a) s += red[a]; *c0p = s; }
  } else {
    int base = ((bid - 257)*256 + t) * 4;
    const float4 v = *reinterpret_cast<const float4*>(Wv + base);
    ushort4 pk = make_ushort4(f2b(v.x), f2b(v.y), f2b(v.z), f2b(v.w));
    *reinterpret_cast<ushort4*>(Wvb + base) = pk;
  }
}

// ---------------- main fused kernel ----------------
// block = (b, 62-col chunk); tcol 0..63 maps to w = w0-1+tcol (tcol0/63 = halo)
__global__ __launch_bounds__(512, 4) void main_kernel(
    const float* __restrict__ x, const char* __restrict__ ws,
    const float* __restrict__ bv, float* __restrict__ out) {
  const u16* Mb   = (const u16*)ws;
  const u16* Wvb  = (const u16*)(ws + 131072);
  const float* u0 = (const float*)(ws + 262144);
  const float* u1 = (const float*)(ws + 263168);
  const float c0  = *(const float*)(ws + 264192);

  extern __shared__ char lds[];
  u16* Xs   = (u16*)lds;                 // [256][66] bf16 (pad stride 66 -> conflict-free cols)
  u16* Gs   = (u16*)(lds + 33792);       // [256][66] bf16 : G, then Xmix
  float* Ps = (float*)(lds + 67584);     // [3][8][64] partials
  float* ABs = (float*)(lds + 73728);    // [2][64]  alpha, beta
  float* ATs = (float*)(lds + 74240);    // [3][64]  attn weights

  const int bid = blockIdx.x;
  const int b = bid / NCH, cw = bid % NCH;
  const int w0 = cw * WI;
  const int t = threadIdx.x;
  const int wv = t >> 6, l = t & 63;
  const int col = l & 31, half = l >> 5;

  // ---- P0: stage x -> Xs (bf16), zero outside [0,W) ----
  {
    const float* xb = x + (size_t)b * (C_DIM * W_DIM);
    int wg = w0 - 1 + l;
    bool ok = (wg >= 0) & (wg < W_DIM);
    #pragma unroll 4
    for (int it = 0; it < 32; ++it) {
      int c = wv + 8*it;
      float v = ok ? xb[c*W_DIM + wg] : 0.f;
      Xs[c*66 + l] = f2b(v);
    }
  }
  __syncthreads();

  // ---- P1: G = M @ X  (wave wv owns rows [32wv,32wv+32), 2 n-tiles) ----
  {
    f32x16 acc0, acc1;
    #pragma unroll
    for (int r = 0; r < 16; ++r) { acc0[r] = 0.f; acc1[r] = 0.f; }
    const u16* Arow = Mb + (32*wv + col) * 256;
    for (int kk = 0; kk < 16; ++kk) {
      int j0 = 16*kk + 8*half;
      s16x8 a = *reinterpret_cast<const s16x8*>(Arow + j0);
      union { u16 u[8]; s16x8 v; } b0, b1;
      #pragma unroll
      for (int e = 0; e < 8; ++e) {
        b0.u[e] = Xs[(j0+e)*66 + col];
        b1.u[e] = Xs[(j0+e)*66 + 32 + col];
      }
      acc0 = __builtin_amdgcn_mfma_f32_32x32x16_bf16(a, b0.v, acc0, 0, 0, 0);
      acc1 = __builtin_amdgcn_mfma_f32_32x32x16_bf16(a, b1.v, acc1, 0, 0, 0);
    }
    #pragma unroll
    for (int r = 0; r < 16; ++r) {
      int i = 32*wv + (r&3) + 8*(r>>2) + 4*half;
      Gs[i*66 + col]      = f2b(acc0[r]);
      Gs[i*66 + 32 + col] = f2b(acc1[r]);
    }
  }
  __syncthreads();

  // ---- P2: alpha_u = u0.x_u, beta_u = u1.x_u (8-way c-split, cross-wave reduce) ----
  {
    float pa = 0.f, pb = 0.f;
    #pragma unroll 4
    for (int i = 0; i < 32; ++i) {
      int c = 32*wv + i;
      float xv = b2f(Xs[c*66 + l]);
      pa += u0[c] * xv;
      pb += u1[c] * xv;
    }
    Ps[wv*64 + l] = pa;
    Ps[512 + wv*64 + l] = pb;
  }
  __syncthreads();
  if (t < 128) {
    int u = t & 63, which = t >> 6;
    float s = 0.f;
    #pragma unroll
    for (int g = 0; g < 8; ++g) s += Ps[which*512 + g*64 + u];
    ABs[which*64 + u] = s;
  }
  __syncthreads();

  // ---- P3: score dots s_j[w] = x_w . g_{w-1+j}, then softmax(3) ----
  {
    int tm = (l > 0) ? l-1 : 0, tp = (l < 63) ? l+1 : 63;
    float s0 = 0.f, s1 = 0.f, s2 = 0.f;
    #pragma unroll 4
    for (int i = 0; i < 32; ++i) {
      int c = 32*wv + i;
      float xv = b2f(Xs[c*66 + l]);
      s0 += xv * b2f(Gs[c*66 + tm]);
      s1 += xv * b2f(Gs[c*66 + l]);
      s2 += xv * b2f(Gs[c*66 + tp]);
    }
    Ps[wv*64 + l] = s0;
    Ps[512 + wv*64 + l] = s1;
    Ps[1024 + wv*64 + l] = s2;
  }
  __syncthreads();
  if (t < 64) {
    int tc = t;
    if (tc >= 1 && tc <= WI) {
      float d0 = 0.f, d1 = 0.f, d2 = 0.f;
      #pragma unroll
      for (int g = 0; g < 8; ++g) {
        d0 += Ps[g*64 + tc]; d1 += Ps[512 + g*64 + tc]; d2 += Ps[1024 + g*64 + tc];
      }
      int wg = w0 - 1 + tc;
      float beta = ABs[64 + tc];
      float sc0 = (d0 + ABs[tc-1] + beta + c0) * 0.0625f;
      float sc1 = (d1 + ABs[tc]   + beta + c0) * 0.0625f;
      float sc2 = (d2 + ABs[tc+1] + beta + c0) * 0.0625f;
      bool v0 = (wg-1 >= 0) && (wg-1 < W_DIM);
      bool v1 = (wg < W_DIM);
      bool v2 = (wg+1 < W_DIM) && (wg+1 >= 0);
      const float NEG = -1e30f;
      float m = fmaxf(fmaxf(v0 ? sc0 : NEG, v1 ? sc1 : NEG), v2 ? sc2 : NEG);
      float e0 = v0 ? __expf(sc0 - m) : 0.f;
      float e1 = v1 ? __expf(sc1 - m) : 0.f;
      float e2 = v2 ? __expf(sc2 - m) : 0.f;
      float sum = e0 + e1 + e2;
      float inv = (sum > 0.f) ? 1.f / sum : 0.f;
      ATs[tc] = e0*inv; ATs[64+tc] = e1*inv; ATs[128+tc] = e2*inv;
    }
  }
  __syncthreads();

  // ---- P4: Xmix = a0*x_{w-1}+a1*x_w+a2*x_{w+1}  (overwrites Gs) ----
  {
    #pragma unroll 4
    for (int it = 0; it < 32; ++it) {
      int c = wv + 8*it;
      float xm = 0.f;
      if (l >= 1 && l <= WI) {
        float a0 = ATs[l], a1 = ATs[64+l], a2 = ATs[128+l];
        xm = a0 * b2f(Xs[c*66 + l-1]) + a1 * b2f(Xs[c*66 + l]) + a2 * b2f(Xs[c*66 + l+1]);
      }
      Gs[c*66 + l] = f2b(xm);
    }
  }
  __syncthreads();

  // ---- P5: out = Wv @ Xmix + bv, store transposed [c'][w] (coalesced) ----
  {
    f32x16 acc0, acc1;
    #pragma unroll
    for (int r = 0; r < 16; ++r) { acc0[r] = 0.f; acc1[r] = 0.f; }
    const u16* Arow = Wvb + (32*wv + col) * 256;
    for (int kk = 0; kk < 16; ++kk) {
      int j0 = 16*kk + 8*half;
      s16x8 a = *reinterpret_cast<const s16x8*>(Arow + j0);
      union { u16 u[8]; s16x8 v; } b0, b1;
      #pragma unroll
      for (int e = 0; e < 8; ++e) {
        b0.u[e] = Gs[(j0+e)*66 + col];
        b1.u[e] = Gs[(j0+e)*66 + 32 + col];
      }
      acc0 = __builtin_amdgcn_mfma_f32_32x32x16_bf16(a, b0.v, acc0, 0, 0, 0);
      acc1 = __builtin_amdgcn_mfma_f32_32x32x16_bf16(a, b1.v, acc1, 0, 0, 0);
    }
    float* outb = out + (size_t)b * (C_DIM * W_DIM);
    #pragma unroll
    for (int r = 0; r < 16; ++r) {
      int crow = 32*wv + (r&3) + 8*(r>>2) + 4*half;
      float bvv = bv[crow];
      int tc0 = col, tc1 = col + 32;
      int wg0 = w0 - 1 + tc0, wg1 = w0 - 1 + tc1;
      if (tc0 >= 1 && wg0 < W_DIM)  outb[crow*W_DIM + wg0] = acc0[r] + bvv;
      if (tc1 <= WI && wg1 < W_DIM) outb[crow*W_DIM + wg1] = acc1[r] + bvv;
    }
  }
}

extern "C" void kernel_launch(void* const* d_in, const int* in_sizes, int n_in,
                              void* d_out, int out_size, void* d_ws, size_t ws_size,
                              hipStream_t stream) {
  (void)in_sizes; (void)n_in; (void)out_size; (void)ws_size;
  const float* x  = (const float*)d_in[0];
  const float* Wq = (const float*)d_in[1];
  const float* bq = (const float*)d_in[2];
  const float* Wk = (const float*)d_in[3];
  const float* bk = (const float*)d_in[4];
  const float* Wv = (const float*)d_in[5];
  const float* bv = (const float*)d_in[6];
  float* out = (float*)d_out;
  char* ws = (char*)d_ws;   // needs 264196 B

  hipFuncSetAttribute((const void*)main_kernel,
                      hipFuncAttributeMaxDynamicSharedMemorySize, LDS_BYTES);
  prep_kernel<<<321, 256, 0, stream>>>(Wq, bq, Wk, bk, Wv, ws);
  main_kernel<<<16 * NCH, 512, LDS_BYTES, stream>>>(x, ws, bv, out);
}

// Round 2
// 104.376 us; speedup vs baseline: 1.1791x; 1.1791x over previous
//
#include <hip/hip_runtime.h>

#define C_DIM 256
#define W_DIM 4096
#define WI 62            // interior columns per chunk
#define NCH 67           // ceil(4096/62)
#define LDS_BYTES 77056

typedef unsigned short u16;
typedef short s16x8 __attribute__((ext_vector_type(8)));
typedef unsigned short u16x8 __attribute__((ext_vector_type(8)));
typedef float f32x16 __attribute__((ext_vector_type(16)));

__device__ __forceinline__ u16 f2b(float f) {
  unsigned x = __builtin_bit_cast(unsigned, f);
  x = x + 0x7FFFu + ((x >> 16) & 1u);          // RNE to bf16 (inputs finite)
  return (u16)(x >> 16);
}
__device__ __forceinline__ float b2f(u16 u) {
  return __builtin_bit_cast(float, ((unsigned)u) << 16);
}

// ---------------- prep kernel ----------------
// ws layout: [0,131072) M bf16 [256][256]; [131072,262144) Wv bf16;
//            [262144) u0[256] f32; [263168) u1[256] f32; [264192) c0 f32
__global__ __launch_bounds__(256) void prep_kernel(
    const float* __restrict__ Wq, const float* __restrict__ bq,
    const float* __restrict__ Wk, const float* __restrict__ bk,
    const float* __restrict__ Wv, char* __restrict__ ws) {
  u16* Mb   = (u16*)ws;
  u16* Wvb  = (u16*)(ws + 131072);
  float* u0 = (float*)(ws + 262144);
  float* u1 = (float*)(ws + 263168);
  float* c0p = (float*)(ws + 264192);
  int bid = blockIdx.x, t = threadIdx.x;
  if (bid < 256) {
    __shared__ float Wqs[256*17];
    __shared__ float Wks[256*17];
    int i0 = (bid >> 4) << 4, j0 = (bid & 15) << 4;
    for (int it = 0; it < 16; ++it) {
      int e = t + 256*it; int a = e >> 4, ii = e & 15;
      Wqs[a*17+ii] = Wq[a*256 + i0 + ii];
      Wks[a*17+ii] = Wk[a*256 + j0 + ii];
    }
    __syncthreads();
    int ii = t >> 4, jj = t & 15;
    float acc = 0.f;
    #pragma unroll 8
    for (int a = 0; a < 256; ++a) acc += Wqs[a*17+ii] * Wks[a*17+jj];
    Mb[(i0+ii)*256 + j0 + jj] = f2b(acc);
  } else if (bid == 256) {
    int j = t;
    float a0 = 0.f, a1 = 0.f;
    #pragma unroll 4
    for (int a = 0; a < 256; ++a) {
      a0 += bq[a] * Wk[a*256 + j];
      a1 += bk[a] * Wq[a*256 + j];
    }
    u0[j] = a0; u1[j] = a1;
    __shared__ float red[256];
    red[t] = bq[t] * bk[t];
    __syncthreads();
    if (t == 0) { float s = 0.f; for (int a = 0; a < 256; ++a) s += red[a]; *c0p = s; }
  } else {
    int base = ((bid - 257)*256 + t) * 4;
    const float4 v = *reinterpret_cast<const float4*>(Wv + base);
    ushort4 pk = make_ushort4(f2b(v.x), f2b(v.y), f2b(v.z), f2b(v.w));
    *reinterpret_cast<ushort4*>(Wvb + base) = pk;
  }
}

// ---------------- main fused kernel ----------------
// LDS layout (k-packed): T[kk = c>>3][w 0..63][e = c&7] u16, one b128 per (kk,w)
__global__ __launch_bounds__(512, 4) void main_kernel(
    const float* __restrict__ x, const char* __restrict__ ws,
    const float* __restrict__ bv, float* __restrict__ out) {
  const u16* Mb   = (const u16*)ws;
  const u16* Wvb  = (const u16*)(ws + 131072);
  const float* u0 = (const float*)(ws + 262144);
  const float* u1 = (const float*)(ws + 263168);
  const float c0  = *(const float*)(ws + 264192);

  extern __shared__ char lds[];
  u16* Xt    = (u16*)lds;                 // [32][64][8] bf16
  u16* Gt    = (u16*)(lds + 32768);       // [32][64][8] bf16 : G, then Xmix
  float* PsA = (float*)(lds + 65536);     // [2][8][64] alpha/beta partials
  float* PsB = (float*)(lds + 69632);     // [3][8][64] score partials
  float* ABs = (float*)(lds + 75776);     // [2][64]
  float* ATs = (float*)(lds + 76288);     // [3][64]

  const int bid = blockIdx.x;
  const int b = bid / NCH, cw = bid % NCH;
  const int w0 = cw * WI;
  const int t = threadIdx.x;
  const int wv = t >> 6, l = t & 63;
  const int col = l & 31, half = l >> 5;

  // ---- P0: stage x -> Xt (bf16, k-packed), zero outside [0,W) ----
  {
    const float* xb = x + (size_t)b * (C_DIM * W_DIM);
    int wg = w0 - 1 + l;
    bool ok = (wg >= 0) & (wg < W_DIM);
    const float* xp = xb + wg;
    #pragma unroll
    for (int it = 0; it < 4; ++it) {
      int kk = wv + 8*it;
      union { u16 u[8]; u16x8 v; } pk;
      #pragma unroll
      for (int e = 0; e < 8; ++e) {
        int c = kk*8 + e;
        float v = ok ? xp[(size_t)c * W_DIM] : 0.f;
        pk.u[e] = f2b(v);
      }
      *reinterpret_cast<u16x8*>(Xt + (kk*64 + l)*8) = pk.v;
    }
  }
  __syncthreads();

  // ---- P1: G = M @ X (MFMA) ; P2a: alpha/beta partials ----
  {
    f32x16 acc0, acc1;
    #pragma unroll
    for (int r = 0; r < 16; ++r) { acc0[r] = 0.f; acc1[r] = 0.f; }
    const u16* Arow = Mb + (32*wv + col)*256 + 8*half;
    #pragma unroll 4
    for (int kk = 0; kk < 16; ++kk) {
      s16x8 a = *reinterpret_cast<const s16x8*>(Arow + 16*kk);
      int kkidx = 2*kk + half;
      s16x8 b0 = *reinterpret_cast<const s16x8*>(Xt + (kkidx*64 + col)*8);
      s16x8 b1 = *reinterpret_cast<const s16x8*>(Xt + (kkidx*64 + col + 32)*8);
      acc0 = __builtin_amdgcn_mfma_f32_32x32x16_bf16(a, b0, acc0, 0, 0, 0);
      acc1 = __builtin_amdgcn_mfma_f32_32x32x16_bf16(a, b1, acc1, 0, 0, 0);
    }
    // write G to Gt (k-packed); i = 32wv + 8q + 4half + p  ->  kk=4wv+q, e=4half+p
    #pragma unroll
    for (int q = 0; q < 4; ++q) {
      ushort4 g0, g1;
      g0.x = f2b(acc0[4*q+0]); g0.y = f2b(acc0[4*q+1]);
      g0.z = f2b(acc0[4*q+2]); g0.w = f2b(acc0[4*q+3]);
      g1.x = f2b(acc1[4*q+0]); g1.y = f2b(acc1[4*q+1]);
      g1.z = f2b(acc1[4*q+2]); g1.w = f2b(acc1[4*q+3]);
      int rowg = 4*wv + q;
      *reinterpret_cast<ushort4*>(Gt + (rowg*64 + col)*8 + 4*half)      = g0;
      *reinterpret_cast<ushort4*>(Gt + (rowg*64 + col + 32)*8 + 4*half) = g1;
    }
    // P2a: alpha/beta partials (wave wv covers c in [32wv, 32wv+32))
    float pa = 0.f, pb = 0.f;
    #pragma unroll
    for (int kg = 0; kg < 4; ++kg) {
      int kk = 4*wv + kg;
      u16x8 xv8 = *reinterpret_cast<const u16x8*>(Xt + (kk*64 + l)*8);
      #pragma unroll
      for (int e = 0; e < 8; ++e) {
        int c = kk*8 + e;
        float xv = b2f(xv8[e]);
        pa += u0[c] * xv;
        pb += u1[c] * xv;
      }
    }
    PsA[wv*64 + l] = pa;
    PsA[512 + wv*64 + l] = pb;
  }
  __syncthreads();

  // ---- P3a: score partials (reads Xt, Gt) ; P2b: alpha/beta reduce ----
  {
    int tm = (l > 0) ? l-1 : 0, tp = (l < 63) ? l+1 : 63;
    float s0 = 0.f, s1 = 0.f, s2 = 0.f;
    #pragma unroll
    for (int kg = 0; kg < 4; ++kg) {
      int kk = 4*wv + kg;
      u16x8 xv8 = *reinterpret_cast<const u16x8*>(Xt + (kk*64 + l)*8);
      u16x8 gm  = *reinterpret_cast<const u16x8*>(Gt + (kk*64 + tm)*8);
      u16x8 gc  = *reinterpret_cast<const u16x8*>(Gt + (kk*64 + l)*8);
      u16x8 gp  = *reinterpret_cast<const u16x8*>(Gt + (kk*64 + tp)*8);
      #pragma unroll
      for (int e = 0; e < 8; ++e) {
        float xv = b2f(xv8[e]);
        s0 += xv * b2f(gm[e]);
        s1 += xv * b2f(gc[e]);
        s2 += xv * b2f(gp[e]);
      }
    }
    PsB[wv*64 + l] = s0;
    PsB[512 + wv*64 + l] = s1;
    PsB[1024 + wv*64 + l] = s2;
    if (t < 128) {
      int u = t & 63, which = t >> 6;
      float s = 0.f;
      #pragma unroll
      for (int g = 0; g < 8; ++g) s += PsA[which*512 + g*64 + u];
      ABs[which*64 + u] = s;
    }
  }
  __syncthreads();

  // ---- P3b: reduce + softmax(3) ----
  if (t < 64) {
    int tc = t;
    if (tc >= 1 && tc <= WI) {
      float d0 = 0.f, d1 = 0.f, d2 = 0.f;
      #pragma unroll
      for (int g = 0; g < 8; ++g) {
        d0 += PsB[g*64 + tc]; d1 += PsB[512 + g*64 + tc]; d2 += PsB[1024 + g*64 + tc];
      }
      int wg = w0 - 1 + tc;
      float beta = ABs[64 + tc];
      float sc0 = (d0 + ABs[tc-1] + beta + c0) * 0.0625f;
      float sc1 = (d1 + ABs[tc]   + beta + c0) * 0.0625f;
      float sc2 = (d2 + ABs[tc+1] + beta + c0) * 0.0625f;
      bool v0 = (wg-1 >= 0) && (wg-1 < W_DIM);
      bool v1 = (wg < W_DIM);
      bool v2 = (wg+1 < W_DIM) && (wg+1 >= 0);
      const float NEG = -1e30f;
      float m = fmaxf(fmaxf(v0 ? sc0 : NEG, v1 ? sc1 : NEG), v2 ? sc2 : NEG);
      float e0 = v0 ? __expf(sc0 - m) : 0.f;
      float e1 = v1 ? __expf(sc1 - m) : 0.f;
      float e2 = v2 ? __expf(sc2 - m) : 0.f;
      float sum = e0 + e1 + e2;
      float inv = (sum > 0.f) ? 1.f / sum : 0.f;
      ATs[tc] = e0*inv; ATs[64+tc] = e1*inv; ATs[128+tc] = e2*inv;
    }
  }
  __syncthreads();

  // ---- P4: Xmix = a0*x_{w-1}+a1*x_w+a2*x_{w+1} (overwrites Gt) ----
  {
    bool inter = (l >= 1) & (l <= WI);
    float a0 = 0.f, a1 = 0.f, a2 = 0.f;
    if (inter) { a0 = ATs[l]; a1 = ATs[64+l]; a2 = ATs[128+l]; }
    #pragma unroll
    for (int kg = 0; kg < 4; ++kg) {
      int kk = 4*wv + kg;
      union { u16 u[8]; u16x8 v; } pk;
      if (inter) {
        u16x8 xm = *reinterpret_cast<const u16x8*>(Xt + (kk*64 + l-1)*8);
        u16x8 xc = *reinterpret_cast<const u16x8*>(Xt + (kk*64 + l)*8);
        u16x8 xp = *reinterpret_cast<const u16x8*>(Xt + (kk*64 + l+1)*8);
        #pragma unroll
        for (int e = 0; e < 8; ++e)
          pk.u[e] = f2b(a0*b2f(xm[e]) + a1*b2f(xc[e]) + a2*b2f(xp[e]));
      } else {
        #pragma unroll
        for (int e = 0; e < 8; ++e) pk.u[e] = 0;
      }
      *reinterpret_cast<u16x8*>(Gt + (kk*64 + l)*8) = pk.v;
    }
  }
  __syncthreads();

  // ---- P5: out = Wv @ Xmix + bv, coalesced stores ----
  {
    f32x16 acc0, acc1;
    #pragma unroll
    for (int r = 0; r < 16; ++r) { acc0[r] = 0.f; acc1[r] = 0.f; }
    const u16* Arow = Wvb + (32*wv + col)*256 + 8*half;
    #pragma unroll 4
    for (int kk = 0; kk < 16; ++kk) {
      s16x8 a = *reinterpret_cast<const s16x8*>(Arow + 16*kk);
      int kkidx = 2*kk + half;
      s16x8 b0 = *reinterpret_cast<const s16x8*>(Gt + (kkidx*64 + col)*8);
      s16x8 b1 = *reinterpret_cast<const s16x8*>(Gt + (kkidx*64 + col + 32)*8);
      acc0 = __builtin_amdgcn_mfma_f32_32x32x16_bf16(a, b0, acc0, 0, 0, 0);
      acc1 = __builtin_amdgcn_mfma_f32_32x32x16_bf16(a, b1, acc1, 0, 0, 0);
    }
    float* outb = out + (size_t)b * (C_DIM * W_DIM);
    #pragma unroll
    for (int r = 0; r < 16; ++r) {
      int crow = 32*wv + (r&3) + 8*(r>>2) + 4*half;
      float bvv = bv[crow];
      int tc0 = col, tc1 = col + 32;
      int wg0 = w0 - 1 + tc0, wg1 = w0 - 1 + tc1;
      if (tc0 >= 1 && wg0 < W_DIM)  outb[crow*W_DIM + wg0] = acc0[r] + bvv;
      if (tc1 <= WI && wg1 < W_DIM) outb[crow*W_DIM + wg1] = acc1[r] + bvv;
    }
  }
}

extern "C" void kernel_launch(void* const* d_in, const int* in_sizes, int n_in,
                              void* d_out, int out_size, void* d_ws, size_t ws_size,
                              hipStream_t stream) {
  (void)in_sizes; (void)n_in; (void)out_size; (void)ws_size;
  const float* x  = (const float*)d_in[0];
  const float* Wq = (const float*)d_in[1];
  const float* bq = (const float*)d_in[2];
  const float* Wk = (const float*)d_in[3];
  const float* bk = (const float*)d_in[4];
  const float* Wv = (const float*)d_in[5];
  const float* bv = (const float*)d_in[6];
  float* out = (float*)d_out;
  char* ws = (char*)d_ws;   // needs 264196 B

  hipFuncSetAttribute((const void*)main_kernel,
                      hipFuncAttributeMaxDynamicSharedMemorySize, LDS_BYTES);
  prep_kernel<<<321, 256, 0, stream>>>(Wq, bq, Wk, bk, Wv, ws);
  main_kernel<<<16 * NCH, 512, LDS_BYTES, stream>>>(x, ws, bv, out);
}

// Round 3
// 93.093 us; speedup vs baseline: 1.3220x; 1.1212x over previous
//
#include <hip/hip_runtime.h>
#include <hip/hip_bf16.h>

#define C_DIM 256
#define W_DIM 4096
#define WI 62            // interior columns per chunk
#define NCH 67           // ceil(4096/62)
#define LDS_BYTES 49664

typedef unsigned short u16;
typedef short s16x8 __attribute__((ext_vector_type(8)));
typedef unsigned short u16x8 __attribute__((ext_vector_type(8)));
typedef unsigned short u16x4 __attribute__((ext_vector_type(4)));
typedef float f32x16 __attribute__((ext_vector_type(16)));

__device__ __forceinline__ u16 f2b(float f) {
  return __builtin_bit_cast(u16, __float2bfloat16(f));   // hw RNE cvt
}
__device__ __forceinline__ float b2f(u16 u) {
  return __builtin_bit_cast(float, ((unsigned)u) << 16);
}

// ---------------- prep kernel ----------------
// ws layout: [0,131072) M bf16 [256][256]; [131072,262144) Wv bf16;
//            [262144) u0[256] f32; [263168) u1[256] f32; [264192) c0 f32
__global__ __launch_bounds__(256) void prep_kernel(
    const float* __restrict__ Wq, const float* __restrict__ bq,
    const float* __restrict__ Wk, const float* __restrict__ bk,
    const float* __restrict__ Wv, char* __restrict__ ws) {
  u16* Mb   = (u16*)ws;
  u16* Wvb  = (u16*)(ws + 131072);
  float* u0 = (float*)(ws + 262144);
  float* u1 = (float*)(ws + 263168);
  float* c0p = (float*)(ws + 264192);
  int bid = blockIdx.x, t = threadIdx.x;
  if (bid < 256) {
    __shared__ float Wqs[256*17];
    __shared__ float Wks[256*17];
    int i0 = (bid >> 4) << 4, j0 = (bid & 15) << 4;
    for (int it = 0; it < 16; ++it) {
      int e = t + 256*it; int a = e >> 4, ii = e & 15;
      Wqs[a*17+ii] = Wq[a*256 + i0 + ii];
      Wks[a*17+ii] = Wk[a*256 + j0 + ii];
    }
    __syncthreads();
    int ii = t >> 4, jj = t & 15;
    float acc = 0.f;
    #pragma unroll 8
    for (int a = 0; a < 256; ++a) acc += Wqs[a*17+ii] * Wks[a*17+jj];
    Mb[(i0+ii)*256 + j0 + jj] = f2b(acc);
  } else if (bid == 256) {
    int j = t;
    float a0 = 0.f, a1 = 0.f;
    #pragma unroll 4
    for (int a = 0; a < 256; ++a) {
      a0 += bq[a] * Wk[a*256 + j];
      a1 += bk[a] * Wq[a*256 + j];
    }
    u0[j] = a0; u1[j] = a1;
    __shared__ float red[256];
    red[t] = bq[t] * bk[t];
    __syncthreads();
    if (t == 0) { float s = 0.f; for (int a = 0; a < 256; ++a) s += red[a]; *c0p = s; }
  } else {
    int base = ((bid - 257)*256 + t) * 4;
    const float4 v = *reinterpret_cast<const float4*>(Wv + base);
    ushort4 pk = make_ushort4(f2b(v.x), f2b(v.y), f2b(v.z), f2b(v.w));
    *reinterpret_cast<ushort4*>(Wvb + base) = pk;
  }
}

// ---------------- main fused kernel ----------------
// LDS: Xt [kk=c>>3][w 0..63][e=c&7] bf16 (32KB); PsA [2][8][64] f32;
//      PsB [3][16][64] f32; ABs [2][64] f32.  Total 49664 B -> 3 blocks/CU.
__global__ __launch_bounds__(512, 6) void main_kernel(
    const float* __restrict__ x, const char* __restrict__ ws,
    const float* __restrict__ bv, float* __restrict__ out) {
  const u16* Mb   = (const u16*)ws;
  const u16* Wvb  = (const u16*)(ws + 131072);
  const float* u0 = (const float*)(ws + 262144);
  const float* u1 = (const float*)(ws + 263168);
  const float c0  = *(const float*)(ws + 264192);

  extern __shared__ char lds[];
  u16* Xt    = (u16*)lds;               // [32][64][8] bf16
  float* PsA = (float*)(lds + 32768);   // [2][8][64]
  float* PsB = (float*)(lds + 36864);   // [3][16][64]
  float* ABs = (float*)(lds + 49152);   // [2][64]

  const int bid = blockIdx.x;
  const int b = bid / NCH, cw = bid % NCH;
  const int w0 = cw * WI;
  const int t = threadIdx.x;
  const int wv = t >> 6, l = t & 63;
  const int col = l & 31, half = l >> 5;

  // ---- P0: batch-load x (32 outstanding), stage bf16, alpha/beta partials ----
  {
    const float* xb = x + (size_t)b * (C_DIM * W_DIM);
    int wg = w0 - 1 + l;
    bool ok = (wg >= 0) & (wg < W_DIM);
    const float* xp = xb + wg;
    float xr[32];
    #pragma unroll
    for (int it = 0; it < 4; ++it)
      #pragma unroll
      for (int e = 0; e < 8; ++e) {
        int c = (wv + 8*it)*8 + e;
        xr[it*8+e] = ok ? xp[(size_t)c * W_DIM] : 0.f;
      }
    float pa = 0.f, pb = 0.f;
    #pragma unroll
    for (int it = 0; it < 4; ++it) {
      int kk = wv + 8*it;
      union { u16 u[8]; u16x8 v; } pk;
      #pragma unroll
      for (int e = 0; e < 8; ++e) {
        float v = xr[it*8+e];
        pk.u[e] = f2b(v);
        int c = kk*8 + e;
        pa += u0[c] * v;
        pb += u1[c] * v;
      }
      *reinterpret_cast<u16x8*>(Xt + (kk*64 + l)*8) = pk.v;
    }
    PsA[wv*64 + l] = pa;
    PsA[512 + wv*64 + l] = pb;
  }
  __syncthreads();   // bar1

  // ---- P1: G = M @ X kept in accumulators ----
  f32x16 acc0, acc1;
  #pragma unroll
  for (int r = 0; r < 16; ++r) { acc0[r] = 0.f; acc1[r] = 0.f; }
  {
    const u16* Arow = Mb + (32*wv + col)*256 + 8*half;
    #pragma unroll
    for (int kk = 0; kk < 16; ++kk) {
      s16x8 a = *reinterpret_cast<const s16x8*>(Arow + 16*kk);
      int kx = 2*kk + half;
      s16x8 b0 = *reinterpret_cast<const s16x8*>(Xt + (kx*64 + col)*8);
      s16x8 b1 = *reinterpret_cast<const s16x8*>(Xt + (kx*64 + col + 32)*8);
      acc0 = __builtin_amdgcn_mfma_f32_32x32x16_bf16(a, b0, acc0, 0, 0, 0);
      acc1 = __builtin_amdgcn_mfma_f32_32x32x16_bf16(a, b1, acc1, 0, 0, 0);
    }
  }
  if (t < 128) {   // alpha/beta cross-wave reduce (waves 0-1)
    int u = t & 63, which = t >> 6;
    float s = 0.f;
    #pragma unroll
    for (int g = 0; g < 8; ++g) s += PsA[which*512 + g*64 + u];
    ABs[which*64 + u] = s;
  }

  // ---- P2: score partials from acc regs; G[i][w] feeds s1[w], s0[w+1], s2[w-1] ----
  {
    float s0a=0.f, s1a=0.f, s2a=0.f, s0b=0.f, s1b=0.f, s2b=0.f;
    const int e0 = 4*half;
    const int wmm = (col > 0)  ? col-1  : 0;    // clamped; write predicated off
    const int wpp = (col < 31) ? col+33 : 63;
    #pragma unroll
    for (int q = 0; q < 4; ++q) {
      const u16* base = Xt + (4*wv + q)*64*8 + e0;
      u16x4 xm0 = *reinterpret_cast<const u16x4*>(base + wmm*8);
      u16x4 xc0 = *reinterpret_cast<const u16x4*>(base + col*8);
      u16x4 xp0 = *reinterpret_cast<const u16x4*>(base + (col+1)*8);
      u16x4 xm1 = *reinterpret_cast<const u16x4*>(base + (col+31)*8);
      u16x4 xc1 = *reinterpret_cast<const u16x4*>(base + (col+32)*8);
      u16x4 xp1 = *reinterpret_cast<const u16x4*>(base + wpp*8);
      #pragma unroll
      for (int r4 = 0; r4 < 4; ++r4) {
        float g0 = acc0[4*q + r4], g1 = acc1[4*q + r4];
        s2a += g0 * b2f(xm0[r4]);
        s1a += g0 * b2f(xc0[r4]);
        s0a += g0 * b2f(xp0[r4]);
        s2b += g1 * b2f(xm1[r4]);
        s1b += g1 * b2f(xc1[r4]);
        s0b += g1 * b2f(xp1[r4]);
      }
    }
    float* PB = PsB + (wv*2 + half)*64;
    PB[0*1024 + col+1] = s0a;
    if (col < 31) PB[0*1024 + col+33] = s0b;
    PB[1*1024 + col]    = s1a;
    PB[1*1024 + col+32] = s1b;
    if (col > 0) PB[2*1024 + col-1] = s2a;
    PB[2*1024 + col+31] = s2b;
  }
  __syncthreads();   // bar2

  // ---- P3: per-thread softmax (redundant across wv) + in-wave mix into Xt ----
  {
    float a0 = 0.f, a1 = 0.f, a2 = 0.f;
    const bool interior = (l >= 1) && (l <= WI);
    if (interior) {
      float d0 = 0.f, d1 = 0.f, d2 = 0.f;
      #pragma unroll
      for (int g = 0; g < 16; ++g) {
        d0 += PsB[g*64 + l];
        d1 += PsB[1024 + g*64 + l];
        d2 += PsB[2048 + g*64 + l];
      }
      int wgc = w0 - 1 + l;
      float alm = ABs[l-1], alc = ABs[l], alp = ABs[l+1], be = ABs[64+l];
      float sc0 = (d0 + alm + be + c0) * 0.0625f;
      float sc1 = (d1 + alc + be + c0) * 0.0625f;
      float sc2 = (d2 + alp + be + c0) * 0.0625f;
      bool v0 = (wgc - 1 >= 0);
      bool v1 = (wgc < W_DIM);
      bool v2 = (wgc + 1 < W_DIM);
      if (v1) {
        const float NEG = -1e30f;
        float m = fmaxf(v0 ? sc0 : NEG, fmaxf(sc1, v2 ? sc2 : NEG));
        float e0 = v0 ? __expf(sc0 - m) : 0.f;
        float e1 = __expf(sc1 - m);
        float e2 = v2 ? __expf(sc2 - m) : 0.f;
        float inv = 1.f / (e0 + e1 + e2);
        a0 = e0*inv; a1 = e1*inv; a2 = e2*inv;
      }
    }
    // mix: wave-private rows (kk = 4wv..4wv+3) -> reads precede writes in-wave, no barrier
    u16x8 xmix[4];
    #pragma unroll
    for (int kg = 0; kg < 4; ++kg) {
      const u16* base = Xt + (4*wv + kg)*64*8;
      u16x8 xm = *reinterpret_cast<const u16x8*>(base + (l > 0  ? l-1 : 0 )*8);
      u16x8 xc = *reinterpret_cast<const u16x8*>(base + l*8);
      u16x8 xp = *reinterpret_cast<const u16x8*>(base + (l < 63 ? l+1 : 63)*8);
      union { u16 u[8]; u16x8 v; } pk;
      #pragma unroll
      for (int e = 0; e < 8; ++e)
        pk.u[e] = f2b(a0*b2f(xm[e]) + a1*b2f(xc[e]) + a2*b2f(xp[e]));
      xmix[kg] = pk.v;
    }
    if (interior) {
      #pragma unroll
      for (int kg = 0; kg < 4; ++kg)
        *reinterpret_cast<u16x8*>(Xt + ((4*wv + kg)*64 + l)*8) = xmix[kg];
    }
  }
  __syncthreads();   // bar3

  // ---- P4: out = Wv @ Xmix + bv, coalesced stores ----
  {
    #pragma unroll
    for (int r = 0; r < 16; ++r) { acc0[r] = 0.f; acc1[r] = 0.f; }
    float bvr[16];
    #pragma unroll
    for (int q = 0; q < 4; ++q) {
      float4 t4 = *reinterpret_cast<const float4*>(bv + 32*wv + 8*q + 4*half);
      bvr[4*q+0] = t4.x; bvr[4*q+1] = t4.y; bvr[4*q+2] = t4.z; bvr[4*q+3] = t4.w;
    }
    const u16* Arow = Wvb + (32*wv + col)*256 + 8*half;
    #pragma unroll
    for (int kk = 0; kk < 16; ++kk) {
      s16x8 a = *reinterpret_cast<const s16x8*>(Arow + 16*kk);
      int kx = 2*kk + half;
      s16x8 b0 = *reinterpret_cast<const s16x8*>(Xt + (kx*64 + col)*8);
      s16x8 b1 = *reinterpret_cast<const s16x8*>(Xt + (kx*64 + col + 32)*8);
      acc0 = __builtin_amdgcn_mfma_f32_32x32x16_bf16(a, b0, acc0, 0, 0, 0);
      acc1 = __builtin_amdgcn_mfma_f32_32x32x16_bf16(a, b1, acc1, 0, 0, 0);
    }
    float* outb = out + (size_t)b * (C_DIM * W_DIM);
    int wg0 = w0 - 1 + col, wg1 = wg0 + 32;
    bool st0 = (col >= 1) && (wg0 < W_DIM);
    bool st1 = (col <= 30) && (wg1 < W_DIM);
    #pragma unroll
    for (int r = 0; r < 16; ++r) {
      int crow = 32*wv + (r&3) + 8*(r>>2) + 4*half;
      if (st0) outb[(size_t)crow*W_DIM + wg0] = acc0[r] + bvr[r];
      if (st1) outb[(size_t)crow*W_DIM + wg1] = acc1[r] + bvr[r];
    }
  }
}

extern "C" void kernel_launch(void* const* d_in, const int* in_sizes, int n_in,
                              void* d_out, int out_size, void* d_ws, size_t ws_size,
                              hipStream_t stream) {
  (void)in_sizes; (void)n_in; (void)out_size; (void)ws_size;
  const float* x  = (const float*)d_in[0];
  const float* Wq = (const float*)d_in[1];
  const float* bq = (const float*)d_in[2];
  const float* Wk = (const float*)d_in[3];
  const float* bk = (const float*)d_in[4];
  const float* Wv = (const float*)d_in[5];
  const float* bv = (const float*)d_in[6];
  float* out = (float*)d_out;
  char* ws = (char*)d_ws;   // needs 264196 B

  hipFuncSetAttribute((const void*)main_kernel,
                      hipFuncAttributeMaxDynamicSharedMemorySize, LDS_BYTES);
  prep_kernel<<<321, 256, 0, stream>>>(Wq, bq, Wk, bk, Wv, ws);
  main_kernel<<<16 * NCH, 512, LDS_BYTES, stream>>>(x, ws, bv, out);
}